// Round 6
// baseline (58.424 us; speedup 1.0000x reference)
//
#include <hip/hip_runtime.h>
#include <hip/hip_bf16.h>
#include <math.h>

#define N_NODES 2048
#define FIN 128
#define FOUT 64
#define BS 8
#define ALPHA 0.2f

typedef __attribute__((ext_vector_type(8))) short short8v;
typedef __attribute__((ext_vector_type(4))) float f32x4;

__device__ __forceinline__ unsigned int pack2bf(float a, float b) {
  __hip_bfloat162 t = __float22bfloat162_rn(make_float2(a, b));
  unsigned int r;
  __builtin_memcpy(&r, &t, 4);
  return r;
}

__device__ __forceinline__ float elu_f(float v) {
  return v > 0.f ? v : expm1f(v);
}

// ---------------- gat_prep: h + s1/s2 + bf16-fragment pack + mask pack --------
// 2048 blocks x 256 threads (4 waves) = 8 blocks/CU (full 32 waves/CU).
// Block bx: b = bx>>8, nt = bx&255 -> rows n0=nt*8 .. n0+7 of batch b.
// Wave w: rows n0+2w, n0+2w+1 (2 independent chains x 2 f-split accs; W shared).
// Mask: block bx packs adjacency row bx (bijective, no redundancy).
__global__ __launch_bounds__(256, 8) void gat_prep(const float* __restrict__ x,
                                                   const int* __restrict__ adj,
                                                   const float* __restrict__ W,
                                                   const float* __restrict__ a,
                                                   short* __restrict__ hp,
                                                   float* __restrict__ s1,
                                                   float* __restrict__ s2,
                                                   unsigned int* __restrict__ mask32) {
  const int bx = blockIdx.x;            // 0..2047
  const int b = bx >> 8;                // batch
  const int nt = bx & 255;              // 8-row tile within batch
  const int t = threadIdx.x;
  const int w = t >> 6, lane = t & 63;

  __shared__ float h_lds[8][64];

  // ---- h: 2 rows per wave, lane = output channel o ----
  const int n0 = nt * 8;
  const float* xr0 = x + ((long long)b * N_NODES + n0 + 2 * w) * FIN;
  const float* xr1 = xr0 + FIN;
  float acc00 = 0.f, acc01 = 0.f, acc10 = 0.f, acc11 = 0.f;
  #pragma unroll 4
  for (int f = 0; f < FIN; f += 8) {
    const float4 xa0 = *reinterpret_cast<const float4*>(xr0 + f);
    const float4 xa1 = *reinterpret_cast<const float4*>(xr0 + f + 4);
    const float4 xb0 = *reinterpret_cast<const float4*>(xr1 + f);
    const float4 xb1 = *reinterpret_cast<const float4*>(xr1 + f + 4);
    #pragma unroll
    for (int q = 0; q < 4; q++) {
      const float w0 = W[(f + q) * FOUT + lane];
      const float w1 = W[(f + 4 + q) * FOUT + lane];
      const float xa0q = (q == 0) ? xa0.x : (q == 1) ? xa0.y : (q == 2) ? xa0.z : xa0.w;
      const float xa1q = (q == 0) ? xa1.x : (q == 1) ? xa1.y : (q == 2) ? xa1.z : xa1.w;
      const float xb0q = (q == 0) ? xb0.x : (q == 1) ? xb0.y : (q == 2) ? xb0.z : xb0.w;
      const float xb1q = (q == 0) ? xb1.x : (q == 1) ? xb1.y : (q == 2) ? xb1.z : xb1.w;
      acc00 = fmaf(xa0q, w0, acc00);
      acc01 = fmaf(xa1q, w1, acc01);
      acc10 = fmaf(xb0q, w0, acc10);
      acc11 = fmaf(xb1q, w1, acc11);
    }
  }
  const float hA = acc00 + acc01;       // row n0+2w
  const float hB = acc10 + acc11;       // row n0+2w+1
  h_lds[2 * w + 0][lane] = hA;
  h_lds[2 * w + 1][lane] = hB;

  // ---- s1/s2 for the two rows ----
  {
    const float a1v = a[lane], a2v = a[FOUT + lane];
    float p0 = hA * a1v, p1 = hB * a1v;
    float q0 = hA * a2v, q1 = hB * a2v;
    #pragma unroll
    for (int off = 32; off > 0; off >>= 1) {
      p0 += __shfl_xor(p0, off); p1 += __shfl_xor(p1, off);
      q0 += __shfl_xor(q0, off); q1 += __shfl_xor(q1, off);
    }
    if (lane == 0) {
      const long long base = (long long)b * N_NODES + n0 + 2 * w;
      s1[base + 0] = p0; s1[base + 1] = p1;
      s2[base + 0] = q0; s2[base + 1] = q1;
    }
  }

  // ---- mask pack: adjacency row bx; wave w covers cols w*512 .. w*512+511 ----
  {
    const int* ar = adj + (long long)bx * N_NODES + w * 512;
    unsigned int* mw = mask32 + bx * 64 + w * 16;
    #pragma unroll
    for (int c = 0; c < 8; ++c) {
      const unsigned long long bal = __ballot(ar[c * 64 + lane] > 0);
      if (lane == 0) mw[2 * c] = (unsigned int)bal;
      if (lane == 1) mw[2 * c + 1] = (unsigned int)(bal >> 32);
    }
  }

  __syncthreads();

  // ---- pack 8x64 tile -> bf16 B-fragment slots; wave w = ct, lanes 0..15 ----
  // tile (b, jt=nt>>2), k-group kg = nt&3; element (e=local row, o=ct*16+cl):
  // hp[((tile*64 + kg*16 + cl) * 8 + e]
  if (lane < 16) {
    const int ct = w;
    const int kg = nt & 3;
    const int jt = nt >> 2;
    union { short8v v; unsigned int u[4]; } o;
    #pragma unroll
    for (int i = 0; i < 4; ++i)
      o.u[i] = pack2bf(h_lds[2 * i][ct * 16 + lane], h_lds[2 * i + 1][ct * 16 + lane]);
    *reinterpret_cast<short8v*>(
        hp + (((long long)(b * 256 + jt * 4 + ct)) * 64 + kg * 16 + lane) * 8) = o.v;
  }
}

// ---------------- gat_attn: fused p-gen (regs) + MFMA PV + row-sum MFMA -------
// (unchanged from R5 — control)
__global__ __launch_bounds__(512) void gat_attn(const unsigned int* __restrict__ mask32,
                                                const short* __restrict__ hp,
                                                const float* __restrict__ s1g,
                                                const float* __restrict__ s2g,
                                                float* __restrict__ out) {
  const int b = blockIdx.y;
  const int i0 = blockIdx.x * 16;
  const int t = threadIdx.x;
  const int w = t >> 6, lane = t & 63;
  const int kg = lane >> 4, rl = lane & 15;

  __shared__ float red[8][16 * 64];   // 32 KB
  __shared__ float ps[8][16];

  const float s1v = s1g[b * N_NODES + i0 + rl];
  const float* s2B = s2g + b * N_NODES;
  const unsigned int* mrow = mask32 + (i0 + rl) * 64;
  const short8v* hpB = reinterpret_cast<const short8v*>(hp) + (long long)b * 16384;

  f32x4 acc0 = {0.f, 0.f, 0.f, 0.f};
  f32x4 acc1 = {0.f, 0.f, 0.f, 0.f};
  f32x4 acc2 = {0.f, 0.f, 0.f, 0.f};
  f32x4 acc3 = {0.f, 0.f, 0.f, 0.f};
  f32x4 accS = {0.f, 0.f, 0.f, 0.f};
  union { short8v v; unsigned int u[4]; } ones;
  #pragma unroll
  for (int i = 0; i < 4; ++i) ones.u[i] = 0x3F803F80u;

  for (int jt = w; jt < 64; jt += 8) {
    const short8v* hpt = hpB + jt * 256;
    const short8v b0 = hpt[0 * 64 + lane];
    const short8v b1 = hpt[1 * 64 + lane];
    const short8v b2 = hpt[2 * 64 + lane];
    const short8v b3 = hpt[3 * 64 + lane];
    const float4 sa = *reinterpret_cast<const float4*>(s2B + jt * 32 + kg * 8);
    const float4 sb = *reinterpret_cast<const float4*>(s2B + jt * 32 + kg * 8 + 4);
    const unsigned int m = mrow[jt] >> (kg * 8);
    const float s2e[8] = {sa.x, sa.y, sa.z, sa.w, sb.x, sb.y, sb.z, sb.w};
    float p[8];
    #pragma unroll
    for (int e = 0; e < 8; e++) {
      float sc = s1v + s2e[e];
      sc = fmaxf(sc, ALPHA * sc);                 // leaky-relu
      p[e] = ((m >> e) & 1u) ? __expf(sc) : 0.f;
    }
    union { short8v v; unsigned int u[4]; } af;
    #pragma unroll
    for (int i = 0; i < 4; ++i) af.u[i] = pack2bf(p[2 * i], p[2 * i + 1]);
    acc0 = __builtin_amdgcn_mfma_f32_16x16x32_bf16(af.v, b0, acc0, 0, 0, 0);
    acc1 = __builtin_amdgcn_mfma_f32_16x16x32_bf16(af.v, b1, acc1, 0, 0, 0);
    acc2 = __builtin_amdgcn_mfma_f32_16x16x32_bf16(af.v, b2, acc2, 0, 0, 0);
    acc3 = __builtin_amdgcn_mfma_f32_16x16x32_bf16(af.v, b3, acc3, 0, 0, 0);
    accS = __builtin_amdgcn_mfma_f32_16x16x32_bf16(af.v, ones.v, accS, 0, 0, 0);
  }

  #pragma unroll
  for (int r = 0; r < 4; r++) {
    red[w][(kg * 4 + r) * 64 + 0 * 16 + rl] = acc0[r];
    red[w][(kg * 4 + r) * 64 + 1 * 16 + rl] = acc1[r];
    red[w][(kg * 4 + r) * 64 + 2 * 16 + rl] = acc2[r];
    red[w][(kg * 4 + r) * 64 + 3 * 16 + rl] = acc3[r];
  }
  if (rl == 0) {
    #pragma unroll
    for (int r = 0; r < 4; r++) ps[w][kg * 4 + r] = accS[r];
  }
  __syncthreads();

  // epilogue: 512 threads; thread -> (row = t>>5, cols c2, c2+1); sum 8 stripes
  const int row = t >> 5;
  const int c2 = (t & 31) * 2;
  float den = 0.f, v0 = 0.f, v1 = 0.f;
  #pragma unroll
  for (int s = 0; s < 8; ++s) {
    den += ps[s][row];
    const float* rp = &red[s][row * 64 + c2];
    v0 += rp[0]; v1 += rp[1];
  }
  const float inv = 1.0f / den;
  float2 ov;
  ov.x = elu_f(v0 * inv);
  ov.y = elu_f(v1 * inv);
  *reinterpret_cast<float2*>(
      out + ((long long)b * N_NODES + i0 + row) * FOUT + c2) = ov;
}

extern "C" void kernel_launch(void* const* d_in, const int* in_sizes, int n_in,
                              void* d_out, int out_size, void* d_ws, size_t ws_size,
                              hipStream_t stream) {
  const float* x   = (const float*)d_in[0];
  const int*   adj = (const int*)d_in[1];
  const float* W   = (const float*)d_in[2];
  const float* a   = (const float*)d_in[3];
  float* out = (float*)d_out;

  short* hp = (short*)d_ws;                                        // BS*N*FOUT bf16 = 2 MB
  float* s1 = (float*)(hp + (long long)BS * N_NODES * FOUT);       // BS*N f32
  float* s2 = s1 + BS * N_NODES;                                   // BS*N f32
  unsigned int* mask32 = (unsigned int*)(s2 + BS * N_NODES);       // N*64 u32 = 512 KB

  gat_prep<<<2048, 256, 0, stream>>>(x, adj, W, a, hp, s1, s2, mask32);
  gat_attn<<<dim3(N_NODES / 16, BS), 512, 0, stream>>>(mask32, hp, s1, s2, out);
}

// Round 7
// 46.512 us; speedup vs baseline: 1.2561x; 1.2561x over previous
//
#include <hip/hip_runtime.h>
#include <hip/hip_bf16.h>
#include <math.h>

#define N_NODES 2048
#define FIN 128
#define FOUT 64
#define BS 8
#define ALPHA 0.2f

typedef __attribute__((ext_vector_type(8))) short short8v;
typedef __attribute__((ext_vector_type(4))) float f32x4;

__device__ __forceinline__ short f2bf_s(float f) {
  unsigned u = __float_as_uint(f);
  unsigned r = (u + 0x7FFFu + ((u >> 16) & 1u)) >> 16;   // RNE
  return (short)r;
}
__device__ __forceinline__ float bf2f(short s) {
  return __uint_as_float(((unsigned)(unsigned short)s) << 16);
}
__device__ __forceinline__ unsigned int pack2bf(float a, float b) {
  __hip_bfloat162 t = __float22bfloat162_rn(make_float2(a, b));
  unsigned int r;
  __builtin_memcpy(&r, &t, 4);
  return r;
}
__device__ __forceinline__ float elu_f(float v) {
  return v > 0.f ? v : expm1f(v);
}

// ---------------- w_pack: W -> bf16 hi/lo B-fragment layout (once per call) ---
// 1 block, 256 threads = 4 waves; wave = k-step ks. Fragment (ks*4+ct):
// lane (kg=l>>4, col=l&15), elem e <-> W[ks*32 + kg*8 + e][ct*16 + col].
__global__ __launch_bounds__(256) void w_pack(const float* __restrict__ W,
                                              short* __restrict__ whi,
                                              short* __restrict__ wlo) {
  const int ks = threadIdx.x >> 6;
  const int lane = threadIdx.x & 63;
  const int kg = lane >> 4, col = lane & 15;
  for (int ct = 0; ct < 4; ++ct) {
    short8v hi, lo;
    #pragma unroll
    for (int e = 0; e < 8; ++e) {
      const float wv = W[(ks * 32 + kg * 8 + e) * FOUT + ct * 16 + col];
      const short h = f2bf_s(wv);
      hi[e] = h;
      lo[e] = f2bf_s(wv - bf2f(h));
    }
    const int frag = ks * 4 + ct;
    *reinterpret_cast<short8v*>(whi + ((long long)frag * 64 + lane) * 8) = hi;
    *reinterpret_cast<short8v*>(wlo + ((long long)frag * 64 + lane) * 8) = lo;
  }
}

// ---------------- gat_prep: MFMA h + s1/s2 + hp pack + mask pack --------------
// 1024 blocks x 256 threads (4 waves). Block: b = bx>>7, 16-row tile i0.
// Wave w = column tile ct=w. h = 3-term hi/lo MFMA (~fp32 accuracy).
// Mask: block bx packs adjacency rows 2bx, 2bx+1 (bijective).
__global__ __launch_bounds__(256, 4) void gat_prep(const float* __restrict__ x,
                                                   const int* __restrict__ adj,
                                                   const short* __restrict__ whi,
                                                   const short* __restrict__ wlo,
                                                   const float* __restrict__ a,
                                                   short* __restrict__ hp,
                                                   float* __restrict__ s1,
                                                   float* __restrict__ s2,
                                                   unsigned int* __restrict__ mask32) {
  const int bx = blockIdx.x;            // 0..1023
  const int b = bx >> 7;
  const int t16 = bx & 127;
  const int i0 = t16 * 16;
  const int w = threadIdx.x >> 6, lane = threadIdx.x & 63;
  const int kg = lane >> 4, rl = lane & 15;

  __shared__ float h_lds[16][68];

  // ---- mask pack: rows 2bx + (w>>1), column half (w&1) ----
  {
    const int row = 2 * bx + (w >> 1);
    const int* ar = adj + (long long)row * N_NODES + (w & 1) * 1024;
    unsigned int* mw = mask32 + row * 64 + (w & 1) * 32;
    #pragma unroll 4
    for (int c = 0; c < 16; ++c) {
      const unsigned long long bal = __ballot(ar[c * 64 + lane] > 0);
      if (lane == 0) mw[2 * c] = (unsigned int)bal;
      if (lane == 1) mw[2 * c + 1] = (unsigned int)(bal >> 32);
    }
  }

  // ---- h tile via 3-term MFMA: A-frag lane (kg,rl): row=rl, k=kg*8+e ----
  const float* xB = x + ((long long)b * N_NODES + i0 + rl) * FIN + kg * 8;
  f32x4 ahh = {0.f, 0.f, 0.f, 0.f};
  f32x4 ahl = {0.f, 0.f, 0.f, 0.f};
  f32x4 alh = {0.f, 0.f, 0.f, 0.f};
  #pragma unroll
  for (int ks = 0; ks < 4; ++ks) {
    const float4 xa = *reinterpret_cast<const float4*>(xB + ks * 32);
    const float4 xb = *reinterpret_cast<const float4*>(xB + ks * 32 + 4);
    const float xf[8] = {xa.x, xa.y, xa.z, xa.w, xb.x, xb.y, xb.z, xb.w};
    short8v xh, xl;
    #pragma unroll
    for (int e = 0; e < 8; ++e) {
      const short hsh = f2bf_s(xf[e]);
      xh[e] = hsh;
      xl[e] = f2bf_s(xf[e] - bf2f(hsh));
    }
    const short8v bh = *reinterpret_cast<const short8v*>(whi + ((long long)((ks * 4 + w) * 64 + lane)) * 8);
    const short8v bl = *reinterpret_cast<const short8v*>(wlo + ((long long)((ks * 4 + w) * 64 + lane)) * 8);
    ahh = __builtin_amdgcn_mfma_f32_16x16x32_bf16(xh, bh, ahh, 0, 0, 0);
    ahl = __builtin_amdgcn_mfma_f32_16x16x32_bf16(xh, bl, ahl, 0, 0, 0);
    alh = __builtin_amdgcn_mfma_f32_16x16x32_bf16(xl, bh, alh, 0, 0, 0);
  }
  const f32x4 acc = (ahh + ahl) + alh;
  // C/D: col = l&15 -> o = w*16+rl ; row = kg*4 + r
  #pragma unroll
  for (int r = 0; r < 4; ++r)
    h_lds[kg * 4 + r][w * 16 + rl] = acc[r];

  __syncthreads();

  // ---- s1/s2: wave w reduces rows 4w..4w+3 ----
  {
    const float a1v = a[lane], a2v = a[FOUT + lane];
    #pragma unroll
    for (int rr = 0; rr < 4; ++rr) {
      const float hv = h_lds[4 * w + rr][lane];
      float p = hv * a1v, q = hv * a2v;
      #pragma unroll
      for (int off = 32; off > 0; off >>= 1) {
        p += __shfl_xor(p, off);
        q += __shfl_xor(q, off);
      }
      if (lane == 0) {
        s1[(long long)b * N_NODES + i0 + 4 * w + rr] = p;
        s2[(long long)b * N_NODES + i0 + 4 * w + rr] = q;
      }
    }
  }

  // ---- hp pack: wave w = ct; this 16-row tile is k-half kh of hp tile jt ----
  if (lane < 32) {
    const int jt = t16 >> 1, kh = t16 & 1;
    const int kgl = lane >> 4, col = lane & 15;
    union { short8v v; unsigned int u[4]; } o;
    #pragma unroll
    for (int i = 0; i < 4; ++i)
      o.u[i] = pack2bf(h_lds[kgl * 8 + 2 * i][w * 16 + col],
                       h_lds[kgl * 8 + 2 * i + 1][w * 16 + col]);
    *reinterpret_cast<short8v*>(
        hp + (((long long)(b * 256 + jt * 4 + w)) * 64 + (kh * 2 + kgl) * 16 + col) * 8) = o.v;
  }
}

// ---------------- gat_attn: fused p-gen (regs) + MFMA PV + row-sum MFMA -------
// (unchanged — control)
__global__ __launch_bounds__(512) void gat_attn(const unsigned int* __restrict__ mask32,
                                                const short* __restrict__ hp,
                                                const float* __restrict__ s1g,
                                                const float* __restrict__ s2g,
                                                float* __restrict__ out) {
  const int b = blockIdx.y;
  const int i0 = blockIdx.x * 16;
  const int t = threadIdx.x;
  const int w = t >> 6, lane = t & 63;
  const int kg = lane >> 4, rl = lane & 15;

  __shared__ float red[8][16 * 64];   // 32 KB
  __shared__ float ps[8][16];

  const float s1v = s1g[b * N_NODES + i0 + rl];
  const float* s2B = s2g + b * N_NODES;
  const unsigned int* mrow = mask32 + (i0 + rl) * 64;
  const short8v* hpB = reinterpret_cast<const short8v*>(hp) + (long long)b * 16384;

  f32x4 acc0 = {0.f, 0.f, 0.f, 0.f};
  f32x4 acc1 = {0.f, 0.f, 0.f, 0.f};
  f32x4 acc2 = {0.f, 0.f, 0.f, 0.f};
  f32x4 acc3 = {0.f, 0.f, 0.f, 0.f};
  f32x4 accS = {0.f, 0.f, 0.f, 0.f};
  union { short8v v; unsigned int u[4]; } ones;
  #pragma unroll
  for (int i = 0; i < 4; ++i) ones.u[i] = 0x3F803F80u;

  for (int jt = w; jt < 64; jt += 8) {
    const short8v* hpt = hpB + jt * 256;
    const short8v b0 = hpt[0 * 64 + lane];
    const short8v b1 = hpt[1 * 64 + lane];
    const short8v b2 = hpt[2 * 64 + lane];
    const short8v b3 = hpt[3 * 64 + lane];
    const float4 sa = *reinterpret_cast<const float4*>(s2B + jt * 32 + kg * 8);
    const float4 sb = *reinterpret_cast<const float4*>(s2B + jt * 32 + kg * 8 + 4);
    const unsigned int m = mrow[jt] >> (kg * 8);
    const float s2e[8] = {sa.x, sa.y, sa.z, sa.w, sb.x, sb.y, sb.z, sb.w};
    float p[8];
    #pragma unroll
    for (int e = 0; e < 8; e++) {
      float sc = s1v + s2e[e];
      sc = fmaxf(sc, ALPHA * sc);                 // leaky-relu
      p[e] = ((m >> e) & 1u) ? __expf(sc) : 0.f;
    }
    union { short8v v; unsigned int u[4]; } af;
    #pragma unroll
    for (int i = 0; i < 4; ++i) af.u[i] = pack2bf(p[2 * i], p[2 * i + 1]);
    acc0 = __builtin_amdgcn_mfma_f32_16x16x32_bf16(af.v, b0, acc0, 0, 0, 0);
    acc1 = __builtin_amdgcn_mfma_f32_16x16x32_bf16(af.v, b1, acc1, 0, 0, 0);
    acc2 = __builtin_amdgcn_mfma_f32_16x16x32_bf16(af.v, b2, acc2, 0, 0, 0);
    acc3 = __builtin_amdgcn_mfma_f32_16x16x32_bf16(af.v, b3, acc3, 0, 0, 0);
    accS = __builtin_amdgcn_mfma_f32_16x16x32_bf16(af.v, ones.v, accS, 0, 0, 0);
  }

  #pragma unroll
  for (int r = 0; r < 4; r++) {
    red[w][(kg * 4 + r) * 64 + 0 * 16 + rl] = acc0[r];
    red[w][(kg * 4 + r) * 64 + 1 * 16 + rl] = acc1[r];
    red[w][(kg * 4 + r) * 64 + 2 * 16 + rl] = acc2[r];
    red[w][(kg * 4 + r) * 64 + 3 * 16 + rl] = acc3[r];
  }
  if (rl == 0) {
    #pragma unroll
    for (int r = 0; r < 4; r++) ps[w][kg * 4 + r] = accS[r];
  }
  __syncthreads();

  const int row = t >> 5;
  const int c2 = (t & 31) * 2;
  float den = 0.f, v0 = 0.f, v1 = 0.f;
  #pragma unroll
  for (int s = 0; s < 8; ++s) {
    den += ps[s][row];
    const float* rp = &red[s][row * 64 + c2];
    v0 += rp[0]; v1 += rp[1];
  }
  const float inv = 1.0f / den;
  float2 ov;
  ov.x = elu_f(v0 * inv);
  ov.y = elu_f(v1 * inv);
  *reinterpret_cast<float2*>(
      out + ((long long)b * N_NODES + i0 + row) * FOUT + c2) = ov;
}

extern "C" void kernel_launch(void* const* d_in, const int* in_sizes, int n_in,
                              void* d_out, int out_size, void* d_ws, size_t ws_size,
                              hipStream_t stream) {
  const float* x   = (const float*)d_in[0];
  const int*   adj = (const int*)d_in[1];
  const float* W   = (const float*)d_in[2];
  const float* a   = (const float*)d_in[3];
  float* out = (float*)d_out;

  short* hp = (short*)d_ws;                                        // 2 MB
  float* s1 = (float*)(hp + (long long)BS * N_NODES * FOUT);       // 64 KB
  float* s2 = s1 + BS * N_NODES;                                   // 64 KB
  unsigned int* mask32 = (unsigned int*)(s2 + BS * N_NODES);       // 512 KB
  short* whi = (short*)(mask32 + N_NODES * 64);                    // 16 KB
  short* wlo = whi + 16 * 64 * 8;                                  // 16 KB

  w_pack<<<1, 256, 0, stream>>>(W, whi, wlo);
  gat_prep<<<1024, 256, 0, stream>>>(x, adj, whi, wlo, a, hp, s1, s2, mask32);
  gat_attn<<<dim3(N_NODES / 16, BS), 512, 0, stream>>>(mask32, hp, s1, s2, out);
}

// Round 8
// 36.802 us; speedup vs baseline: 1.5875x; 1.2638x over previous
//
#include <hip/hip_runtime.h>
#include <hip/hip_bf16.h>
#include <math.h>

#define N_NODES 2048
#define FIN 128
#define FOUT 64
#define BS 8
#define ALPHA 0.2f

typedef __attribute__((ext_vector_type(8))) short short8v;
typedef __attribute__((ext_vector_type(4))) float f32x4;

__device__ __forceinline__ short f2bf_s(float f) {
  unsigned u = __float_as_uint(f);
  unsigned r = (u + 0x7FFFu + ((u >> 16) & 1u)) >> 16;   // RNE
  return (short)r;
}
__device__ __forceinline__ float bf2f(short s) {
  return __uint_as_float(((unsigned)(unsigned short)s) << 16);
}
__device__ __forceinline__ unsigned int pack2bf(float a, float b) {
  __hip_bfloat162 t = __float22bfloat162_rn(make_float2(a, b));
  unsigned int r;
  __builtin_memcpy(&r, &t, 4);
  return r;
}
__device__ __forceinline__ float elu_f(float v) {
  return v > 0.f ? v : expm1f(v);
}

// ---------------- gat_prep: MFMA h + s1/s2 + hp pack + mask pack --------------
// 1024 blocks x 256 threads (4 waves). Block: b = bx>>7, 16-row tile i0.
// Wave w = column tile ct=w. h = 3-term hi/lo MFMA (~fp32 accuracy).
// W fragments (hi/lo, own ct only) computed per-wave in registers (W is L1-hot).
// Mask: block bx packs adjacency rows 2bx, 2bx+1 (bijective).
__global__ __launch_bounds__(256, 4) void gat_prep(const float* __restrict__ x,
                                                   const int* __restrict__ adj,
                                                   const float* __restrict__ W,
                                                   const float* __restrict__ a,
                                                   short* __restrict__ hp,
                                                   float* __restrict__ s1,
                                                   float* __restrict__ s2,
                                                   unsigned int* __restrict__ mask32) {
  const int bx = blockIdx.x;            // 0..1023
  const int b = bx >> 7;
  const int t16 = bx & 127;
  const int i0 = t16 * 16;
  const int w = threadIdx.x >> 6, lane = threadIdx.x & 63;
  const int kg = lane >> 4, rl = lane & 15;

  __shared__ float h_lds[16][68];

  // ---- W fragments for this wave's ct = w: frag (ks), elem e = W[ks*32+kg*8+e][w*16+rl]
  short8v bh[4], bl[4];
  #pragma unroll
  for (int ks = 0; ks < 4; ++ks) {
    #pragma unroll
    for (int e = 0; e < 8; ++e) {
      const float wv = W[(ks * 32 + kg * 8 + e) * FOUT + w * 16 + rl];
      const short hsh = f2bf_s(wv);
      bh[ks][e] = hsh;
      bl[ks][e] = f2bf_s(wv - bf2f(hsh));
    }
  }

  // ---- mask pack: rows 2bx + (w>>1), column half (w&1) ----
  {
    const int row = 2 * bx + (w >> 1);
    const int* ar = adj + (long long)row * N_NODES + (w & 1) * 1024;
    unsigned int* mw = mask32 + row * 64 + (w & 1) * 32;
    #pragma unroll 4
    for (int c = 0; c < 16; ++c) {
      const unsigned long long bal = __ballot(ar[c * 64 + lane] > 0);
      if (lane == 0) mw[2 * c] = (unsigned int)bal;
      if (lane == 1) mw[2 * c + 1] = (unsigned int)(bal >> 32);
    }
  }

  // ---- h tile via 3-term MFMA: A-frag lane (kg,rl): row=rl, k=kg*8+e ----
  const float* xB = x + ((long long)b * N_NODES + i0 + rl) * FIN + kg * 8;
  f32x4 ahh = {0.f, 0.f, 0.f, 0.f};
  f32x4 ahl = {0.f, 0.f, 0.f, 0.f};
  f32x4 alh = {0.f, 0.f, 0.f, 0.f};
  #pragma unroll
  for (int ks = 0; ks < 4; ++ks) {
    const float4 xa = *reinterpret_cast<const float4*>(xB + ks * 32);
    const float4 xb = *reinterpret_cast<const float4*>(xB + ks * 32 + 4);
    const float xf[8] = {xa.x, xa.y, xa.z, xa.w, xb.x, xb.y, xb.z, xb.w};
    short8v xh, xl;
    #pragma unroll
    for (int e = 0; e < 8; ++e) {
      const short hsh = f2bf_s(xf[e]);
      xh[e] = hsh;
      xl[e] = f2bf_s(xf[e] - bf2f(hsh));
    }
    ahh = __builtin_amdgcn_mfma_f32_16x16x32_bf16(xh, bh[ks], ahh, 0, 0, 0);
    ahl = __builtin_amdgcn_mfma_f32_16x16x32_bf16(xh, bl[ks], ahl, 0, 0, 0);
    alh = __builtin_amdgcn_mfma_f32_16x16x32_bf16(xl, bh[ks], alh, 0, 0, 0);
  }
  const f32x4 acc = (ahh + ahl) + alh;
  // C/D: col = l&15 -> o = w*16+rl ; row = kg*4 + r
  #pragma unroll
  for (int r = 0; r < 4; ++r)
    h_lds[kg * 4 + r][w * 16 + rl] = acc[r];

  __syncthreads();

  // ---- s1/s2: wave w reduces rows 4w..4w+3 ----
  {
    const float a1v = a[lane], a2v = a[FOUT + lane];
    #pragma unroll
    for (int rr = 0; rr < 4; ++rr) {
      const float hv = h_lds[4 * w + rr][lane];
      float p = hv * a1v, q = hv * a2v;
      #pragma unroll
      for (int off = 32; off > 0; off >>= 1) {
        p += __shfl_xor(p, off);
        q += __shfl_xor(q, off);
      }
      if (lane == 0) {
        s1[(long long)b * N_NODES + i0 + 4 * w + rr] = p;
        s2[(long long)b * N_NODES + i0 + 4 * w + rr] = q;
      }
    }
  }

  // ---- hp pack: wave w = ct; this 16-row tile is k-half kh of hp tile jt ----
  if (lane < 32) {
    const int jt = t16 >> 1, kh = t16 & 1;
    const int kgl = lane >> 4, col = lane & 15;
    union { short8v v; unsigned int u[4]; } o;
    #pragma unroll
    for (int i = 0; i < 4; ++i)
      o.u[i] = pack2bf(h_lds[kgl * 8 + 2 * i][w * 16 + col],
                       h_lds[kgl * 8 + 2 * i + 1][w * 16 + col]);
    *reinterpret_cast<short8v*>(
        hp + (((long long)(b * 256 + jt * 4 + w)) * 64 + (kh * 2 + kgl) * 16 + col) * 8) = o.v;
  }
}

// ---------------- gat_attn: 32 rows/block, 2 A-frags/wave, 8 j-stripes --------
// Grid (64 i-tiles of 32 rows, 8 b), 512 threads = 8 waves, wave w = j-stripe w.
// B-loads shared by both A-frags -> hp L2 traffic halved vs 16-row blocks.
// A-frag: lane l holds p[row=l&15][k=(l>>4)*8+e]. C/D: col(o)=l&15, row(i)=(l>>4)*4+r.
__global__ __launch_bounds__(512) void gat_attn(const unsigned int* __restrict__ mask32,
                                                const short* __restrict__ hp,
                                                const float* __restrict__ s1g,
                                                const float* __restrict__ s2g,
                                                float* __restrict__ out) {
  const int b = blockIdx.y;
  const int i0 = blockIdx.x * 32;
  const int t = threadIdx.x;
  const int w = t >> 6, lane = t & 63;
  const int kg = lane >> 4, rl = lane & 15;

  __shared__ float red[8][16 * 64];   // 32 KB (reused for both row-halves)
  __shared__ float ps[8][16];

  const float s1v1 = s1g[b * N_NODES + i0 + rl];
  const float s1v2 = s1g[b * N_NODES + i0 + 16 + rl];
  const float* s2B = s2g + b * N_NODES;
  const unsigned int* mrow1 = mask32 + (i0 + rl) * 64;
  const unsigned int* mrow2 = mask32 + (i0 + 16 + rl) * 64;
  const short8v* hpB = reinterpret_cast<const short8v*>(hp) + (long long)b * 16384;

  f32x4 a10 = {0.f, 0.f, 0.f, 0.f}, a11 = {0.f, 0.f, 0.f, 0.f};
  f32x4 a12 = {0.f, 0.f, 0.f, 0.f}, a13 = {0.f, 0.f, 0.f, 0.f};
  f32x4 a20 = {0.f, 0.f, 0.f, 0.f}, a21 = {0.f, 0.f, 0.f, 0.f};
  f32x4 a22 = {0.f, 0.f, 0.f, 0.f}, a23 = {0.f, 0.f, 0.f, 0.f};
  f32x4 aS1 = {0.f, 0.f, 0.f, 0.f}, aS2 = {0.f, 0.f, 0.f, 0.f};
  union { short8v v; unsigned int u[4]; } ones;
  #pragma unroll
  for (int i = 0; i < 4; ++i) ones.u[i] = 0x3F803F80u;

  for (int jt = w; jt < 64; jt += 8) {
    const short8v* hpt = hpB + jt * 256;
    const short8v b0 = hpt[0 * 64 + lane];
    const short8v b1 = hpt[1 * 64 + lane];
    const short8v b2 = hpt[2 * 64 + lane];
    const short8v b3 = hpt[3 * 64 + lane];
    const float4 sa = *reinterpret_cast<const float4*>(s2B + jt * 32 + kg * 8);
    const float4 sb = *reinterpret_cast<const float4*>(s2B + jt * 32 + kg * 8 + 4);
    const unsigned int m1 = mrow1[jt] >> (kg * 8);
    const unsigned int m2 = mrow2[jt] >> (kg * 8);
    const float s2e[8] = {sa.x, sa.y, sa.z, sa.w, sb.x, sb.y, sb.z, sb.w};
    float p1[8], p2[8];
    #pragma unroll
    for (int e = 0; e < 8; e++) {
      float sc1 = s1v1 + s2e[e];
      float sc2 = s2e[e] + s1v2;
      sc1 = fmaxf(sc1, ALPHA * sc1);
      sc2 = fmaxf(sc2, ALPHA * sc2);
      p1[e] = ((m1 >> e) & 1u) ? __expf(sc1) : 0.f;
      p2[e] = ((m2 >> e) & 1u) ? __expf(sc2) : 0.f;
    }
    union { short8v v; unsigned int u[4]; } af1, af2;
    #pragma unroll
    for (int i = 0; i < 4; ++i) {
      af1.u[i] = pack2bf(p1[2 * i], p1[2 * i + 1]);
      af2.u[i] = pack2bf(p2[2 * i], p2[2 * i + 1]);
    }
    a10 = __builtin_amdgcn_mfma_f32_16x16x32_bf16(af1.v, b0, a10, 0, 0, 0);
    a20 = __builtin_amdgcn_mfma_f32_16x16x32_bf16(af2.v, b0, a20, 0, 0, 0);
    a11 = __builtin_amdgcn_mfma_f32_16x16x32_bf16(af1.v, b1, a11, 0, 0, 0);
    a21 = __builtin_amdgcn_mfma_f32_16x16x32_bf16(af2.v, b1, a21, 0, 0, 0);
    a12 = __builtin_amdgcn_mfma_f32_16x16x32_bf16(af1.v, b2, a12, 0, 0, 0);
    a22 = __builtin_amdgcn_mfma_f32_16x16x32_bf16(af2.v, b2, a22, 0, 0, 0);
    a13 = __builtin_amdgcn_mfma_f32_16x16x32_bf16(af1.v, b3, a13, 0, 0, 0);
    a23 = __builtin_amdgcn_mfma_f32_16x16x32_bf16(af2.v, b3, a23, 0, 0, 0);
    aS1 = __builtin_amdgcn_mfma_f32_16x16x32_bf16(af1.v, ones.v, aS1, 0, 0, 0);
    aS2 = __builtin_amdgcn_mfma_f32_16x16x32_bf16(af2.v, ones.v, aS2, 0, 0, 0);
  }

  // ---- phase 1: rows i0..i0+15 ----
  #pragma unroll
  for (int r = 0; r < 4; r++) {
    red[w][(kg * 4 + r) * 64 + 0 * 16 + rl] = a10[r];
    red[w][(kg * 4 + r) * 64 + 1 * 16 + rl] = a11[r];
    red[w][(kg * 4 + r) * 64 + 2 * 16 + rl] = a12[r];
    red[w][(kg * 4 + r) * 64 + 3 * 16 + rl] = a13[r];
  }
  if (rl == 0) {
    #pragma unroll
    for (int r = 0; r < 4; r++) ps[w][kg * 4 + r] = aS1[r];
  }
  __syncthreads();
  {
    const int row = t >> 5;
    const int c2 = (t & 31) * 2;
    float den = 0.f, v0 = 0.f, v1 = 0.f;
    #pragma unroll
    for (int s = 0; s < 8; ++s) {
      den += ps[s][row];
      const float* rp = &red[s][row * 64 + c2];
      v0 += rp[0]; v1 += rp[1];
    }
    const float inv = 1.0f / den;
    float2 ov;
    ov.x = elu_f(v0 * inv);
    ov.y = elu_f(v1 * inv);
    *reinterpret_cast<float2*>(
        out + ((long long)b * N_NODES + i0 + row) * FOUT + c2) = ov;
  }
  __syncthreads();

  // ---- phase 2: rows i0+16..i0+31 ----
  #pragma unroll
  for (int r = 0; r < 4; r++) {
    red[w][(kg * 4 + r) * 64 + 0 * 16 + rl] = a20[r];
    red[w][(kg * 4 + r) * 64 + 1 * 16 + rl] = a21[r];
    red[w][(kg * 4 + r) * 64 + 2 * 16 + rl] = a22[r];
    red[w][(kg * 4 + r) * 64 + 3 * 16 + rl] = a23[r];
  }
  if (rl == 0) {
    #pragma unroll
    for (int r = 0; r < 4; r++) ps[w][kg * 4 + r] = aS2[r];
  }
  __syncthreads();
  {
    const int row = t >> 5;
    const int c2 = (t & 31) * 2;
    float den = 0.f, v0 = 0.f, v1 = 0.f;
    #pragma unroll
    for (int s = 0; s < 8; ++s) {
      den += ps[s][row];
      const float* rp = &red[s][row * 64 + c2];
      v0 += rp[0]; v1 += rp[1];
    }
    const float inv = 1.0f / den;
    float2 ov;
    ov.x = elu_f(v0 * inv);
    ov.y = elu_f(v1 * inv);
    *reinterpret_cast<float2*>(
        out + ((long long)b * N_NODES + i0 + 16 + row) * FOUT + c2) = ov;
  }
}

extern "C" void kernel_launch(void* const* d_in, const int* in_sizes, int n_in,
                              void* d_out, int out_size, void* d_ws, size_t ws_size,
                              hipStream_t stream) {
  const float* x   = (const float*)d_in[0];
  const int*   adj = (const int*)d_in[1];
  const float* W   = (const float*)d_in[2];
  const float* a   = (const float*)d_in[3];
  float* out = (float*)d_out;

  short* hp = (short*)d_ws;                                        // 2 MB
  float* s1 = (float*)(hp + (long long)BS * N_NODES * FOUT);       // 64 KB
  float* s2 = s1 + BS * N_NODES;                                   // 64 KB
  unsigned int* mask32 = (unsigned int*)(s2 + BS * N_NODES);       // 512 KB

  gat_prep<<<1024, 256, 0, stream>>>(x, adj, W, a, hp, s1, s2, mask32);
  gat_attn<<<dim3(N_NODES / 32, BS), 512, 0, stream>>>(mask32, hp, s1, s2, out);
}